// Round 6
// baseline (503.368 us; speedup 1.0000x reference)
//
#include <hip/hip_runtime.h>
#include <hip/hip_bf16.h>

// out = x @ (W + B@A)^T + bias, fused:  W' = W + B@A (bf16), xb = bf16(x),
// out = xb @ W'^T + bias (fp32).  M=8192, N=4096, K=4096.
// GEMM: 256x256 tile, BK=64, 8 waves (2Mx4N), 128 KiB LDS dbuf, both-sides
// XOR swizzle, ROUND-4 VERIFIED 8-barrier skeleton (BAR; lgkmcnt(0); MFMA;
// BAR per phase). Changes vs round 4 (round 5's minimal barriers RACED and
// is reverted): builtin MFMA (native AGPR accum, no asm "v" copies), stages
// consolidated in q2/q3 -> uniform 2-tile lookahead, vmcnt(8) per tile.

#define M_TOT 8192
#define NDIM  4096
#define KDIM  4096
#define RANK  16

typedef float f4 __attribute__((ext_vector_type(4)));
typedef short s8v __attribute__((ext_vector_type(8)));   // 8 bf16 payloads

// ---------- helpers ----------

static __device__ __forceinline__ unsigned short f2bf(float f) {
  union { float f; unsigned u; } v; v.f = f;
  unsigned r = v.u + 0x7FFF + ((v.u >> 16) & 1);   // RNE
  return (unsigned short)(r >> 16);
}
static __device__ __forceinline__ unsigned pack2(float lo, float hi) {
  return (unsigned)f2bf(lo) | ((unsigned)f2bf(hi) << 16);
}

#define GLOAD_LDS16(gaddr, laddr)                                              \
  __builtin_amdgcn_global_load_lds(                                            \
      (__attribute__((address_space(1))) void*)(gaddr),                        \
      (__attribute__((address_space(3))) void*)(laddr), 16, 0, 0)

// ---------- kernel 1: cast x fp32 -> bf16 bits, 8 elems/thread ----------

__global__ __launch_bounds__(256) void cast_x_kernel(
    const float* __restrict__ in, unsigned short* __restrict__ out, int n8) {
  int i = blockIdx.x * blockDim.x + threadIdx.x;
  int stride = gridDim.x * blockDim.x;
  for (; i < n8; i += stride) {
    const float4* p = (const float4*)in + (size_t)i * 2;
    float4 a = p[0];
    float4 b = p[1];
    uint4 o;
    o.x = pack2(a.x, a.y);
    o.y = pack2(a.z, a.w);
    o.z = pack2(b.x, b.y);
    o.w = pack2(b.z, b.w);
    ((uint4*)out)[i] = o;
  }
}

// ---------- kernel 2: W' = W + B@A -> bf16. 4096 blocks, 4 o-rows/thread ---

__global__ __launch_bounds__(256) void fuse_w_kernel(
    const float* __restrict__ W, const float* __restrict__ A,
    const float* __restrict__ B, unsigned short* __restrict__ Wb) {
  const int t = threadIdx.x;
  const int i = blockIdx.x * 1024 + t * 4;
  const int o0 = blockIdx.y * 4;

  f4 areg[RANK];
#pragma unroll
  for (int r = 0; r < RANK; ++r)
    areg[r] = *(const f4*)(A + (size_t)r * KDIM + i);

#pragma unroll
  for (int oo = 0; oo < 4; ++oo) {
    const int o = o0 + oo;
    f4 acc = *(const f4*)(W + (size_t)o * KDIM + i);
#pragma unroll
    for (int r = 0; r < RANK; ++r)
      acc += B[o * RANK + r] * areg[r];
    uint2 pk;
    pk.x = pack2(acc.x, acc.y);
    pk.y = pack2(acc.z, acc.w);
    *(uint2*)(Wb + (size_t)o * KDIM + i) = pk;
  }
}

// ---------- kernel 3: 256x256 8-barrier bf16 GEMM ----------
// LDS element map (per 32768-elem buffer): A0=0, A1=8192, B0=16384, B1=24576.
// Storage rule (both-sides involution): element (row, colblk cs) lives at
// LDS[row*64 + (cs ^ (row&7))*8]. Staged via linear dest + pre-swizzled
// global source column; read with the same XOR (rule #21).
// Stage schedule: ALL stages for tile t+2 (cur buf) issue in q2 (B0,B1 —
// after BAR_a retiring all-waves B reads) and q3 (A0,A1 — after BAR_b
// retiring all-waves A reads). 16 loads in flight; vmcnt(8) at tile end
// retires exactly tile t+1's 8.

#define BAR()   __builtin_amdgcn_s_barrier()
#define WAITL() do { asm volatile("s_waitcnt lgkmcnt(0)" ::: "memory");        \
                     __builtin_amdgcn_sched_barrier(0); } while (0)
#define VMC8()  asm volatile("s_waitcnt vmcnt(8)" ::: "memory")
#define PRIO(x) __builtin_amdgcn_s_setprio(x)

__global__ __launch_bounds__(512, 2) void gemm_kernel(
    const unsigned short* __restrict__ Xb,   // [M][K] bf16 bits
    const unsigned short* __restrict__ Wb,   // [N][K] bf16 bits
    const float* __restrict__ bias,
    float* __restrict__ C) {
  __shared__ __attribute__((aligned(16))) unsigned short lds[65536];  // 128 KiB

  const int tid  = threadIdx.x;
  const int w    = tid >> 6;
  const int lane = tid & 63;
  const int fr   = lane & 15;
  const int fq   = lane >> 4;

  // XCD-aware swizzle: nwg=512 = 8 XCDs x 64 contiguous (bijective).
  const unsigned orig = blockIdx.x;
  const unsigned wg   = (orig & 7) * 64 + (orig >> 3);
  const int brow = (int)(wg >> 4) * 256;   // 32 M-tiles
  const int bcol = (int)(wg & 15) * 256;   // 16 N-tiles

  const int wrow = (w >> 2) * 128;   // wave M offset in tile
  const int wcol = (w & 3) * 64;     // wave N offset in tile

  // Read-side swizzle (element units; colblk = 8 elems = 16 B):
  const int swz = (fr & 7) * 8;
  const int ck0 = (fq * 8) ^ swz;          // kk=0 (cs=fq)
  const int ck1 = (fq * 8 + 32) ^ swz;     // kk=1 (cs=fq+4)

  // Staging: thread stages 16 B at linear LDS offset w*512 + lane*8 (+j*4096).
  // Logical row = j*64 + w*8 + (lane>>3); source colblk pre-inverse-swizzled
  // by row&7 = lane>>3.
  const int srow = (w << 3) + (lane >> 3);
  const int sdst = (w << 9) + (lane << 3);
  const int scol = ((lane & 7) ^ (lane >> 3)) << 3;
  const unsigned short* Xs = Xb + (size_t)(brow + srow) * KDIM + scol;
  const unsigned short* Ws = Wb + (size_t)(bcol + srow) * KDIM + scol;

  f4 acc[8][4] = {};
  s8v af[8], bf0[4], bf1[4];

  // reg: 0=A0 (rows 0-127), 1=A1 (128-255), 2=B0, 3=B1
  auto stage = [&](int T, int reg) {
    const int k0 = (T & 63) << 6;   // wrap past K end: valid mem, never read
    const unsigned short* s =
        (reg < 2 ? Xs : Ws) + (size_t)(reg & 1) * 128 * KDIM + k0;
    unsigned short* d = &lds[((T & 1) << 15) + (reg << 13) + sdst];
    GLOAD_LDS16(s, d);
    GLOAD_LDS16(s + 64 * KDIM, d + 4096);
  };

  auto lda = [&](int base, int mh) {
#pragma unroll
    for (int mi = 0; mi < 4; ++mi) {
      const int row = wrow + mh * 64 + mi * 16 + fr;
      af[mi * 2 + 0] = *(const s8v*)&lds[base + row * 64 + ck0];
      af[mi * 2 + 1] = *(const s8v*)&lds[base + row * 64 + ck1];
    }
  };
  auto ldb = [&](s8v* bf, int base, int nh) {
#pragma unroll
    for (int ni = 0; ni < 2; ++ni) {
      const int row = wcol + nh * 32 + ni * 16 + fr;
      bf[ni * 2 + 0] = *(const s8v*)&lds[base + 16384 + row * 64 + ck0];
      bf[ni * 2 + 1] = *(const s8v*)&lds[base + 16384 + row * 64 + ck1];
    }
  };
  auto mm = [&](int mh, int nh, const s8v* bf) {
#pragma unroll
    for (int kk = 0; kk < 2; ++kk)
#pragma unroll
      for (int mi = 0; mi < 4; ++mi)
#pragma unroll
        for (int ni = 0; ni < 2; ++ni)
          acc[mh * 4 + mi][nh * 2 + ni] =
              __builtin_amdgcn_mfma_f32_16x16x32_bf16(
                  af[mi * 2 + kk], bf[ni * 2 + kk],
                  acc[mh * 4 + mi][nh * 2 + ni], 0, 0, 0);
  };

  // Prologue: tiles 0 and 1 fully staged (16 loads); vmcnt(8) = tile 0 done.
  stage(0, 0); stage(0, 2); stage(0, 1); stage(0, 3);
  stage(1, 0); stage(1, 2); stage(1, 1); stage(1, 3);
  VMC8();
  BAR();

  for (int t = 0; t < 64; ++t) {
    const int base = (t & 1) << 15;
    // q0: read A(mh=0) + B(nh=0); MFMA quadrant (0,0)
    lda(base, 0); ldb(bf0, base, 0);
    BAR(); WAITL(); PRIO(1); mm(0, 0, bf0); PRIO(0); BAR();
    // q1: read B(nh=1); MFMA (0,1)
    ldb(bf1, base, 1);
    BAR(); WAITL(); PRIO(1); mm(0, 1, bf1); PRIO(0); BAR();   // BAR_a: B reads retired
    // q2: read A(mh=1); stage cur-buf B0,B1 of t+2; MFMA (1,1)
    lda(base, 1);
    stage(t + 2, 2); stage(t + 2, 3);
    BAR(); WAITL(); PRIO(1); mm(1, 1, bf1); PRIO(0); BAR();   // BAR_b: A reads retired
    // q3: stage cur-buf A0,A1 of t+2; MFMA (1,0); counted vmcnt
    stage(t + 2, 0); stage(t + 2, 1);
    BAR(); PRIO(1); mm(1, 0, bf0); PRIO(0);
    VMC8();
    BAR();
  }

  // Epilogue: C/D layout col = fr, row = fq*4 + reg.
  float bv[4];
#pragma unroll
  for (int n = 0; n < 4; ++n) bv[n] = bias[bcol + wcol + n * 16 + fr];
#pragma unroll
  for (int m = 0; m < 8; ++m) {
#pragma unroll
    for (int jr = 0; jr < 4; ++jr) {
      const int row = brow + wrow + m * 16 + fq * 4 + jr;
      float* cp = C + (size_t)row * NDIM + bcol + wcol + fr;
      cp[0]  = acc[m][0][jr] + bv[0];
      cp[16] = acc[m][1][jr] + bv[1];
      cp[32] = acc[m][2][jr] + bv[2];
      cp[48] = acc[m][3][jr] + bv[3];
    }
  }
}

// ---------- launch ----------

extern "C" void kernel_launch(void* const* d_in, const int* in_sizes, int n_in,
                              void* d_out, int out_size, void* d_ws, size_t ws_size,
                              hipStream_t stream) {
  const float* x    = (const float*)d_in[0];
  const float* W    = (const float*)d_in[1];
  const float* bias = (const float*)d_in[2];
  const float* A    = (const float*)d_in[3];
  const float* B    = (const float*)d_in[4];
  float* out = (float*)d_out;

  unsigned short* xb = (unsigned short*)d_ws;                  // 64 MiB
  unsigned short* wb = xb + (size_t)M_TOT * KDIM;              // 32 MiB

  cast_x_kernel<<<4096, 256, 0, stream>>>(x, xb, (M_TOT * KDIM) / 8);
  fuse_w_kernel<<<dim3(KDIM / 1024, NDIM / 4), 256, 0, stream>>>(W, A, B, wb);
  gemm_kernel<<<512, 512, 0, stream>>>(xb, wb, bias, out);
}